// Round 7
// baseline (108.838 us; speedup 1.0000x reference)
//
#include <hip/hip_runtime.h>
#include <math.h>

#define TL 2048
#define PI_D 3.14159265358979323846

typedef __attribute__((ext_vector_type(8))) short short8v;
typedef __attribute__((ext_vector_type(4))) float float4v;

#define B_OFF 16384        // A dbuf occupies smem[0..16384)
#define BRS 4368           // B replica row stride bytes (2176 elems*2 + 16 pad)

__device__ __forceinline__ unsigned short bf16_rne(float f) {
  unsigned u = __float_as_uint(f);
  return (unsigned short)((u + 0x7FFFu + ((u >> 16) & 1u)) >> 16);
}

// tap value k[d], d = idx - 2047
__device__ __forceinline__ float tap_val(int idx, double beta, double wv) {
  int d = idx - 2047;
  double x = PI_D * (double)d / 6144.0 - beta;
  if (fabs(x) < 1e-9) return 1.0f;
  double c = wv * (cos(x) / sin(x));
  if (d & 1) c = -c;
  return (float)c;
}

// ---------------------------------------------------------------------------
// K1 (336 blocks):
//  b in [0,64):   frame kernel b -> BFrep bf16 shift-replicas (G-layout).
//  b in [64,80):  event kernel (b-64) -> kerC exclusive tap prefix (mask id).
//  b in [80,336): shift_time, u-split 2x: idx=b-80: p=idx>>4, tile=idx&15
//                 (128 t per tile), thread = (tl=tid&127, uh=tid>>7); output
//                 written bf16 into tsh_swz PRE-SWIZZLED layout for gl_lds:
//                 elem(p,t): ph=t>>8, up=t&255, m=up>>3, i=up&7,
//                 D=p*32+(m^(p&7)); tsh_swz[ph*4096 + D*8 + i].
// ---------------------------------------------------------------------------
__global__ __launch_bounds__(256) void build_shift_k(const float* __restrict__ shifts,
                                                     const float* __restrict__ time_in,
                                                     float* __restrict__ kerC,
                                                     unsigned short* __restrict__ BFrep,
                                                     unsigned short* __restrict__ tsh_swz) {
  __shared__ __align__(16) unsigned char sm1[17408];
  __shared__ float wsum[4];
  int b = blockIdx.x;
  int tid = threadIdx.x;
  if (b < 80) {
    float* kf = (float*)sm1;  // 4104 floats
    double s;
    if (b < 64) s = (double)b * (1.0 / 63.0) * (2048.0 / 3.0);
    else        s = (double)shifts[b - 64] * (2048.0 / 3.0);
    double beta = PI_D * s / 3073.0;
    double y = 3072.0 * s / 3073.0;
    double r = y - rint(y);
    double wv = -sin(2.0 * PI_D * r) / 6144.0;
    for (int idx = tid; idx < 4104; idx += 256)
      kf[idx] = (idx < 4095) ? tap_val(idx, beta, wv) : 0.0f;
    __syncthreads();
    if (b < 64) {
      for (int c = tid; c < 4096; c += 256) {
        int sr = c >> 9;
        int m = c & 511;
        int A = 4095 - 8 * m + sr;
        unsigned short out[8];
#pragma unroll
        for (int rr = 0; rr < 8; ++rr) out[rr] = bf16_rne(kf[A - rr]);
        *(short8v*)(BFrep + ((size_t)(b * 8 + sr)) * 4104 + 8 * m) = *(short8v*)out;
      }
    } else {
      float s0 = 0.f;
      int base = tid * 16;
#pragma unroll
      for (int i = 0; i < 16; ++i) s0 += kf[base + i];
      int lane = tid & 63;
      float v = s0;
#pragma unroll
      for (int d = 1; d < 64; d <<= 1) {
        float o = __shfl_up(v, (unsigned)d, 64);
        if (lane >= d) v += o;
      }
      if (lane == 63) wsum[tid >> 6] = v;
      __syncthreads();
      float woff = 0.f;
      for (int k = 0; k < (tid >> 6); ++k) woff += wsum[k];
      float run = v + woff - s0;
      float* crow = kerC + (b - 64) * 4096;
#pragma unroll
      for (int i = 0; i < 16; ++i) {
        crow[base + i] = run;
        run += kf[base + i];
      }
    }
  } else {
    // shift_time, u-split
    int idx = b - 80;
    int p = idx >> 4, tile = idx & 15;
    int t0 = tile * 128;
    float* a = (float*)sm1;             // 2048 f @ 0
    float* kw = (float*)(sm1 + 8192);   // 2176 f @ 8192
    float* partial = (float*)(sm1 + 16896);  // 128 f
    double s = (double)shifts[p] * (2048.0 / 3.0);
    double beta = PI_D * s / 3073.0;
    double y = 3072.0 * s / 3073.0;
    double r = y - rint(y);
    double wv = -sin(2.0 * PI_D * r) / 6144.0;
    for (int i = tid; i < 2048; i += 256) a[i] = time_in[p * 2048 + i];
    for (int i = tid; i < 2175; i += 256) kw[i] = tap_val(t0 + i, beta, wv);
    __syncthreads();
    int tl = tid & 127, uh = tid >> 7;
    int base = tl + 2047 - (uh << 10);
    int u0 = uh << 10;
    float acc = 0.f;
#pragma unroll 8
    for (int u2 = 0; u2 < 1024; ++u2) acc = fmaf(a[u0 + u2], kw[base - u2], acc);
    __syncthreads();
    if (uh == 1) partial[tl] = acc;
    __syncthreads();
    if (uh == 0) {
      acc += partial[tl];
      int t = t0 + tl;
      int phh = t >> 8, up = t & 255;
      int m = up >> 3, i2 = up & 7;
      int D = (p << 5) | (m ^ (p & 7));
      tsh_swz[phh * 4096 + D * 8 + i2] = bf16_rne(acc);
    }
  }
}

// ---------------------------------------------------------------------------
// K2 (1552 blocks):
//  bx in [0,1024): expT via MFMA. j=bx>>4, tB=(bx&15)*128.
//    Prologue: stage FULL B band (8 replicas x 2176 elems, z_lo=1920-tB,
//    row stride 4368 B) + phase-0 A via global_load_lds (tsh_swz is
//    pre-swizzled so LDS dst is linear). Loop 8 phases: issue gl_lds for
//    ph+1 into A-buf^1, compute (K-split 4-slot B ring, 16 MFMA/wave),
//    ONE barrier. Epilogue: cross-wave K reduce in A region.
//  bx in [1024,1040): s-branch MLP.
//  bx in [1040,1552): pos via MFMA (in-register sins, lazy hi/lo W).
// ---------------------------------------------------------------------------
__global__ __launch_bounds__(256) void fused2_k(const unsigned short* __restrict__ tsh_swz,
                                                const unsigned short* __restrict__ BFrep,
                                                float* __restrict__ expT,
                                                const float* __restrict__ w_pos,
                                                const float* __restrict__ b_pos,
                                                float* __restrict__ pos,
                                                const float* __restrict__ shape,
                                                const float* __restrict__ w_layers,
                                                const float* __restrict__ b_layers,
                                                float* __restrict__ s64) {
  __shared__ __align__(16) unsigned char smem[16384 + 8 * BRS];  // 51328 B
  int bx = blockIdx.x;
  int tid = threadIdx.x;
  if (bx < 1024) {
    int j = bx >> 4;
    int tB = (bx & 15) << 7;
    int l = tid & 63, w = tid >> 6;
    int p16 = l & 15, g = l >> 4;
    int srep = l & 7, hb = (l >> 3) & 1;
    int h = w >> 1, kp = w & 1;
    int kc0 = kp << 2;
    int z_lo = 1920 - tB;
    const unsigned short* grow = BFrep + (size_t)j * 8 * 4104;

    // prologue: stage full B band (plain loads)
#pragma unroll
    for (int sr = 0; sr < 8; ++sr) {
      for (int m = tid; m < 272; m += 256) {
        short8v v = *(const short8v*)(grow + sr * 4104 + z_lo + (m << 3));
        *(short8v*)(smem + B_OFF + sr * BRS + (m << 4)) = v;
      }
    }
    // stage A phase 0 into buf 0 via global_load_lds
    auto stage_a = [&](int buf, int ph2) {
#pragma unroll
      for (int it = 0; it < 2; ++it) {
        const unsigned int* src =
            (const unsigned int*)tsh_swz + ((ph2 << 11) + (((it << 8) + tid) << 2));
        unsigned char* dstp = smem + buf * 8192 + (it << 12) + ((tid >> 6) << 10);
        __builtin_amdgcn_global_load_lds(
            (const __attribute__((address_space(1))) unsigned int*)src,
            (__attribute__((address_space(3))) unsigned int*)dstp, 16, 0, 0);
      }
    };
    stage_a(0, 0);
    __syncthreads();

    float4v acc[4];
#pragma unroll
    for (int i = 0; i < 4; ++i) acc[i] = (float4v){0.f, 0.f, 0.f, 0.f};
    int bB2 = B_OFF + srep * BRS + 256 - (hb << 4) + (g << 4) - (h << 7);
    int cur = 0;

    for (int ph = 0; ph < 8; ++ph) {
      if (ph < 7) stage_a(cur ^ 1, ph + 1);
      int fb = bB2 + (ph << 9) + (kc0 << 6);
      short8v W0 = *(const short8v*)(smem + fb);
      short8v W1 = *(const short8v*)(smem + fb - 32);
      short8v W2 = *(const short8v*)(smem + fb - 64);
      short8v W3 = *(const short8v*)(smem + fb - 96);
#pragma unroll
      for (int qq = 0; qq < 4; ++qq) {
        int kc = kc0 + qq;
        if (qq > 0) {
          short8v t2 = W0, t3 = W1;
          W0 = *(const short8v*)(smem + fb + (qq << 6));
          W1 = *(const short8v*)(smem + fb + (qq << 6) - 32);
          W2 = t2;
          W3 = t3;
        }
        int ao = cur * 8192 + (((p16 << 9) + (kc << 6) + (g << 4)) ^ ((p16 & 7) << 4));
        short8v a = *(const short8v*)(smem + ao);
        acc[0] = __builtin_amdgcn_mfma_f32_16x16x32_bf16(a, W0, acc[0], 0, 0, 0);
        acc[1] = __builtin_amdgcn_mfma_f32_16x16x32_bf16(a, W1, acc[1], 0, 0, 0);
        acc[2] = __builtin_amdgcn_mfma_f32_16x16x32_bf16(a, W2, acc[2], 0, 0, 0);
        acc[3] = __builtin_amdgcn_mfma_f32_16x16x32_bf16(a, W3, acc[3], 0, 0, 0);
      }
      __syncthreads();
      cur ^= 1;
    }
    // cross-wave K reduction in A region (kp=1 -> LDS, kp=0 adds and stores)
    if (kp == 1) {
#pragma unroll
      for (int ct = 0; ct < 4; ++ct)
        *(float4v*)(smem + ((((h << 2) + ct) << 6) + l) * 16) = acc[ct];
    }
    __syncthreads();
    if (kp == 0) {
#pragma unroll
      for (int ct = 0; ct < 4; ++ct) {
        float4v o = *(const float4v*)(smem + ((((h << 2) + ct) << 6) + l) * 16);
#pragma unroll
        for (int rr = 0; rr < 4; ++rr) acc[ct][rr] += o[rr];
      }
      int tbase = tB + (h << 6) + p16;
#pragma unroll
      for (int ct = 0; ct < 4; ++ct) {
#pragma unroll
        for (int rr = 0; rr < 4; ++rr) {
          int prow = (g << 2) + rr;
          expT[(size_t)(prow * 64 + j) * TL + tbase + (ct << 4)] = acc[ct][rr];
        }
      }
    }
  } else if (bx < 1040) {
    float(*sA)[33] = (float(*)[33])(smem);
    float(*sB)[33] = (float(*)[33])(smem + 8448);
    float(*W)[33] = (float(*)[33])(smem + 16896);
    float* bb = (float*)(smem + 21120);
    int p = bx - 1024;
    for (int idx = tid; idx < 2048; idx += 256) {
      int c = idx >> 6, f = idx & 63;
      sA[f][c] = shape[p * 2048 + idx];
    }
    int c = tid & 31, fg = tid >> 5;
    for (int ll = 0; ll < 4; ++ll) {
      for (int idx = tid; idx < 1024; idx += 256) W[idx >> 5][idx & 31] = w_layers[ll * 1024 + idx];
      if (tid < 32) bb[tid] = b_layers[ll * 32 + tid];
      __syncthreads();
      float(*cur)[33] = (ll & 1) ? sB : sA;
      float(*nxt)[33] = (ll & 1) ? sA : sB;
#pragma unroll
      for (int i = 0; i < 8; ++i) {
        int f = fg * 8 + i;
        float acc = cur[f][c] + bb[c];
#pragma unroll
        for (int k = 0; k < 32; ++k) acc = fmaf(fmaxf(cur[f][k], 0.f), W[c][k], acc);
        nxt[f][c] = acc;
      }
      __syncthreads();
    }
    for (int idx = tid; idx < 2048; idx += 256) {
      int cc = idx >> 6, f = idx & 63;
      s64[p * 2048 + idx] = fmaxf(sA[f][cc], 0.f);
    }
  } else {
    int l = tid & 63, w = tid >> 6;
    int p16 = l & 15, g = l >> 4;
    int T0 = (bx - 1040) * 64 + w * 16;

    float ttv = (float)(T0 + p16) * (32768.0f / 32767.0f);
    float4v acc0 = {0.f, 0.f, 0.f, 0.f};
    float4v acc1 = {0.f, 0.f, 0.f, 0.f};
#pragma unroll
    for (int kc = 0; kc < 8; ++kc) {
      short8v bh0, bl0, bh1, bl1;
#pragma unroll
      for (int ct = 0; ct < 2; ++ct) {
        const float* wrow = w_pos + (ct * 16 + p16) * 256 + kc * 32 + g * 8;
        float4v w0 = *(const float4v*)(wrow);
        float4v w1 = *(const float4v*)(wrow + 4);
        short8v hv, lv;
#pragma unroll
        for (int i = 0; i < 8; ++i) {
          float vv = (i < 4) ? w0[i] : w1[i - 4];
          unsigned short hbit = bf16_rne(vv);
          float hf = __uint_as_float(((unsigned)hbit) << 16);
          hv[i] = (short)hbit;
          lv[i] = (short)bf16_rne(vv - hf);
        }
        if (ct == 0) { bh0 = hv; bl0 = lv; }
        else         { bh1 = hv; bl1 = lv; }
      }
      short8v ahi, alo;
#pragma unroll
      for (int i = 0; i < 8; ++i) {
        int f = kc * 32 + g * 8 + i;
        float fr = 1e-5f + (float)f * ((0.5f - 1e-5f) / 255.0f);
        float rev = ttv * (0.5f * fr);
        float sv = __builtin_amdgcn_sinf(__builtin_amdgcn_fractf(rev));
        unsigned short hbit = bf16_rne(sv);
        float hf = __uint_as_float(((unsigned)hbit) << 16);
        ahi[i] = (short)hbit;
        alo[i] = (short)bf16_rne(sv - hf);
      }
      acc0 = __builtin_amdgcn_mfma_f32_16x16x32_bf16(ahi, bh0, acc0, 0, 0, 0);
      acc1 = __builtin_amdgcn_mfma_f32_16x16x32_bf16(ahi, bh1, acc1, 0, 0, 0);
      acc0 = __builtin_amdgcn_mfma_f32_16x16x32_bf16(ahi, bl0, acc0, 0, 0, 0);
      acc1 = __builtin_amdgcn_mfma_f32_16x16x32_bf16(ahi, bl1, acc1, 0, 0, 0);
      acc0 = __builtin_amdgcn_mfma_f32_16x16x32_bf16(alo, bh0, acc0, 0, 0, 0);
      acc1 = __builtin_amdgcn_mfma_f32_16x16x32_bf16(alo, bh1, acc1, 0, 0, 0);
    }
    float bp0 = b_pos[p16], bp1 = b_pos[16 + p16];
    float4v o0, o1;
#pragma unroll
    for (int rr = 0; rr < 4; ++rr) {
      o0[rr] = acc0[rr] + bp0;
      o1[rr] = acc1[rr] + bp1;
    }
    int Tr = T0 + g * 4;
    *(float4v*)(pos + (size_t)p16 * 32768 + Tr) = o0;
    *(float4v*)(pos + (size_t)(16 + p16) * 32768 + Tr) = o1;
  }
}

// ---------------------------------------------------------------------------
// env fused with mask: msk[p,j,t] = kerC[p][t+2046-j] - kerC[p][t]
// ---------------------------------------------------------------------------
__global__ __launch_bounds__(256) void env2_k(const float* __restrict__ energy,
                                              const float* __restrict__ props,
                                              const float* __restrict__ expT,
                                              const float* __restrict__ kerC,
                                              float* __restrict__ env) {
  int p = blockIdx.x >> 5, tile = blockIdx.x & 31;
  int tl = threadIdx.x & 63;
  int cg = threadIdx.x >> 6;
  int tC = tile * 64;
  int t = tC + tl;
  __shared__ float E[32][64];
  __shared__ float K[32];
  __shared__ float kcl[2112];
  for (int i = threadIdx.x; i < 2048; i += 256) E[i >> 6][i & 63] = energy[p * 2048 + i];
  const float* crow = kerC + p * 4096;
  for (int i = threadIdx.x; i < 2110; i += 256) kcl[i] = crow[tC + i];
  if (threadIdx.x < 32) {
    float mass = props[(p * 32 + threadIdx.x) * 2];
    float fric = props[(p * 32 + threadIdx.x) * 2 + 1];
    K[threadIdx.x] = fric / (2.0f * mass);
  }
  __syncthreads();
  float acc[8];
  float kk[8];
#pragma unroll
  for (int i = 0; i < 8; ++i) acc[i] = 0.f;
#pragma unroll
  for (int i = 0; i < 8; ++i) kk[i] = K[cg * 8 + i];
  float Ct = kcl[tl];
  const float* xrow = expT + (size_t)p * 64 * TL + t;
  for (int jj = 0; jj < 64; ++jj) {
    float x = xrow[jj * TL];
    float mv = kcl[tl + 2046 - jj] - Ct;
#pragma unroll
    for (int cc = 0; cc < 8; ++cc)
      acc[cc] = fmaf(E[cg * 8 + cc][jj] * mv, __expf(-kk[cc] * x), acc[cc]);
  }
#pragma unroll
  for (int cc = 0; cc < 8; ++cc)
    env[(size_t)(p * 32 + cg * 8 + cc) * TL + t] = acc[cc];
}

// ---------------------------------------------------------------------------
// Final (unchanged)
// ---------------------------------------------------------------------------
__global__ __launch_bounds__(256) void final_k(const float* __restrict__ pos,
                                               const float* __restrict__ s64,
                                               const float* __restrict__ env,
                                               float* __restrict__ out) {
  int gid = blockIdx.x * 256 + threadIdx.x;
  int p = gid >> 15, T = gid & 32767;
  float ft = (float)T + 0.5f;
  float ce = fminf(fmaxf(ft * 0.0625f - 0.5f, 0.f), 2047.f);
  int ie = (int)ce;
  int ie1 = min(ie + 1, 2047);
  float we = ce - (float)ie;
  float cs = fminf(fmaxf(ft * (1.0f / 512.0f) - 0.5f, 0.f), 63.f);
  int is0 = (int)cs;
  int is1 = min(is0 + 1, 63);
  float ws = cs - (float)is0;
  const float* erow = env + (size_t)p * 32 * TL;
  const float* srow = s64 + p * 32 * 64;
  float acc = 0.f;
  for (int c = 0; c < 32; ++c) {
    float pv = pos[(size_t)c * 32768 + T];
    float ev = fmaxf(erow[c * TL + ie] * (1.f - we) + erow[c * TL + ie1] * we, 0.f);
    float sv = srow[c * 64 + is0] * (1.f - ws) + srow[c * 64 + is1] * ws;
    acc += pv * sv * ev;
  }
  out[gid] = acc;
}

extern "C" void kernel_launch(void* const* d_in, const int* in_sizes, int n_in,
                              void* d_out, int out_size, void* d_ws, size_t ws_size,
                              hipStream_t stream) {
  const float* time_in  = (const float*)d_in[0];
  const float* shifts   = (const float*)d_in[1];
  const float* energy   = (const float*)d_in[2];
  const float* shape    = (const float*)d_in[3];
  const float* props    = (const float*)d_in[4];
  const float* w_pos    = (const float*)d_in[5];
  const float* b_pos    = (const float*)d_in[6];
  const float* w_layers = (const float*)d_in[7];
  const float* b_layers = (const float*)d_in[8];

  float* ws = (float*)d_ws;
  float* kerC = ws;                                          // 65536 f
  unsigned short* BFrep = (unsigned short*)(ws + 65536);     // 64*8*4104 u16 = 1050624 f
  unsigned short* tsh_swz = (unsigned short*)(ws + 1116160); // 32768 u16 = 16384 f
  float* expT = ws + 1132544;                                // 2097152 f
  float* env  = ws + 3229696;                                // 1048576 f
  float* pos  = ws + 4278272;                                // 1048576 f
  float* s64  = ws + 5326848;                                // 32768 f
  float* out  = (float*)d_out;

  hipLaunchKernelGGL(build_shift_k, dim3(336), dim3(256), 0, stream,
                     shifts, time_in, kerC, BFrep, tsh_swz);
  hipLaunchKernelGGL(fused2_k, dim3(1552), dim3(256), 0, stream, tsh_swz, BFrep, expT,
                     w_pos, b_pos, pos, shape, w_layers, b_layers, s64);
  hipLaunchKernelGGL(env2_k, dim3(512), dim3(256), 0, stream, energy, props, expT, kerC, env);
  hipLaunchKernelGGL(final_k, dim3(2048), dim3(256), 0, stream, pos, s64, env, out);
}